// Round 5
// baseline (52.055 us; speedup 1.0000x reference)
//
#include <hip/hip_runtime.h>
#include <math.h>

static constexpr int S_LEN = 2048;
static constexpr int KMIX  = 20;
static constexpr int NROWS = 256 * 2048;           // B*S
static constexpr int BLOCK = 256;
static constexpr int RPB   = 128;                  // rows per block (2 lanes/row)
static constexpr int NBLK  = NROWS / RPB;          // 4096
static constexpr float SIGMA_MIN_F = 0.01f;
static constexpr float LOG_2PI_F   = 1.8378770664093453f;
static constexpr float TMAX_LOG_F  = 9.2103403719761836f;  // log(1e4)

#define AS1 __attribute__((address_space(1)))
#define AS3 __attribute__((address_space(3)))

__device__ __forceinline__ void gl_lds16(const float* g, float* l) {
    __builtin_amdgcn_global_load_lds((const AS1 void*)g, (AS3 void*)l, 16, 0, 0);
}

// LDS float layout: lg[2560] sx[2560] sy[2560] sw[2560] mu[5120] xs[648]
static constexpr int OFF_LG = 0;
static constexpr int OFF_SX = 2560;
static constexpr int OFF_SY = 5120;
static constexpr int OFF_SW = 7680;
static constexpr int OFF_MU = 10240;
static constexpr int OFF_XS = 15360;
static constexpr int LDS_FLOATS = 16008;           // 64032 B

__global__ __launch_bounds__(BLOCK) void sketch_loss_kernel(
    const float* __restrict__ xs,
    const float* __restrict__ logits,
    const float* __restrict__ mus,
    const float* __restrict__ sxp,
    const float* __restrict__ syp,
    const float* __restrict__ sxyp,
    const float* __restrict__ pen,
    float* __restrict__ partials)
{
    __shared__ float lds[LDS_FLOATS];
    __shared__ float s_pos[4], s_pen[4];

    const int t = threadIdx.x;
    const long r0 = (long)blockIdx.x * RPB;

    // ---------------- stage: dense global -> LDS (16B per lane, fully coalesced) ----
    {
        const float* gl = logits + r0 * 20;
        const float* gx = sxp    + r0 * 20;
        const float* gy = syp    + r0 * 20;
        const float* gw = sxyp   + r0 * 20;
        const float* gm = mus    + r0 * 40;
        #pragma unroll
        for (int it = 0; it < 3; ++it) {
            const int slot = it * 256 + t;
            if (slot < 640) {
                gl_lds16(gl + slot * 4, lds + OFF_LG + slot * 4);
                gl_lds16(gx + slot * 4, lds + OFF_SX + slot * 4);
                gl_lds16(gy + slot * 4, lds + OFF_SY + slot * 4);
                gl_lds16(gw + slot * 4, lds + OFF_SW + slot * 4);
            }
        }
        #pragma unroll
        for (int it = 0; it < 5; ++it) {
            const int slot = it * 256 + t;
            gl_lds16(gm + slot * 4, lds + OFF_MU + slot * 4);
        }
        // xs window: 128 rows + 2 extra 16B slots to cover row r0+128 (162 slots)
        if (t < 162) {
            long gidx = r0 * 5 + (long)t * 4;
            if (gidx > (long)NROWS * 5 - 4) gidx = (long)NROWS * 5 - 4;  // clamp (final block)
            gl_lds16(xs + gidx, lds + OFF_XS + t * 4);
        }
    }
    __syncthreads();

    // ---------------- compute: 2 lanes per row ----------------
    const int k = t >> 1;            // local row 0..127
    const int h = t & 1;             // K-half
    const long r = r0 + k;

    const int kb = k * 20 + h * 10;  // base float index in 2560-float arrays
    const int mb = k * 40 + h * 20;  // base float index in mu array
    const int k5 = k % 5;            // rotation to scatter LDS banks

    float u[10], tt[10], lv[10];
    #pragma unroll
    for (int i = 0; i < 5; ++i) {
        int cc = i + k5; if (cc >= 5) cc -= 5;
        const float2 l2 = *(const float2*)&lds[OFF_LG + kb + cc * 2];
        const float2 x2 = *(const float2*)&lds[OFF_SX + kb + cc * 2];
        const float2 y2 = *(const float2*)&lds[OFF_SY + kb + cc * 2];
        const float2 w2 = *(const float2*)&lds[OFF_SW + kb + cc * 2];
        const float4 m4 = *(const float4*)&lds[OFF_MU + mb + cc * 4];

        const float rel0 = lds[OFF_XS + (k + 1) * 5 + 0] - lds[OFF_XS + k * 5 + 0]; // provisional; fixed below for wrap
        (void)rel0; // (computed properly outside loop; kept simple here)

        // store raw; math done below after rel known
        lv[2 * i]     = l2.x; lv[2 * i + 1] = l2.y;
        u[2 * i]      = x2.x; u[2 * i + 1]  = x2.y;   // temp: sx
        tt[2 * i]     = y2.x; tt[2 * i + 1] = y2.y;   // temp: sy
        // stash sw & mu in registers via recompute-friendly locals:
        // handled in second loop below using same LDS reads would re-read; instead
        // do full math here — need rel first. So compute rel before this loop.
    }

    // NOTE: the loop above must come after rel; restructured final version below.
    // (dead code eliminated by compiler — real computation follows)

    // ---- per-row scalars from staged xs ----
    const float x0  = lds[OFF_XS + k * 5 + 0];
    const float x1  = lds[OFF_XS + k * 5 + 1];
    const float pt0 = lds[OFF_XS + k * 5 + 2];
    const float pt1 = lds[OFF_XS + k * 5 + 3];
    const float pt2 = lds[OFF_XS + k * 5 + 4];
    float xn0, xn1;
    if ((r & (S_LEN - 1)) == (S_LEN - 1)) {       // sequence wrap: next = seq start
        const float* wsrc = xs + (r - (S_LEN - 1)) * 5;
        xn0 = wsrc[0]; xn1 = wsrc[1];
    } else {
        xn0 = lds[OFF_XS + (k + 1) * 5 + 0];
        xn1 = lds[OFF_XS + (k + 1) * 5 + 1];
    }
    const float rel0 = xn0 - x0;
    const float rel1 = xn1 - x1;

    #pragma unroll
    for (int i = 0; i < 5; ++i) {
        int cc = i + k5; if (cc >= 5) cc -= 5;
        const float2 l2 = *(const float2*)&lds[OFF_LG + kb + cc * 2];
        const float2 x2 = *(const float2*)&lds[OFF_SX + kb + cc * 2];
        const float2 y2 = *(const float2*)&lds[OFF_SY + kb + cc * 2];
        const float2 w2 = *(const float2*)&lds[OFF_SW + kb + cc * 2];
        const float4 m4 = *(const float4*)&lds[OFF_MU + mb + cc * 4];

        #pragma unroll
        for (int e = 0; e < 2; ++e) {
            const float l_  = e ? l2.y : l2.x;
            const float sxv = e ? x2.y : x2.x;
            const float syv = e ? y2.y : y2.x;
            const float swv = e ? w2.y : w2.x;
            const float m0  = e ? m4.z : m4.x;
            const float m1  = e ? m4.w : m4.y;

            const float sx = fmaxf(sxv, SIGMA_MIN_F);
            const float sy = fmaxf(syv, SIGMA_MIN_F);
            const float sw = fminf(fmaxf(swv, -SIGMA_MIN_F), SIGMA_MIN_F);
            const float tc = __builtin_amdgcn_rcpf(sx * sy);
            const float d1 = rel0 - m0;
            const float d2 = rel1 - m1;
            const float z1 = d1 * sy * tc;
            const float z2 = (d2 - sw * z1) * sx * tc;
            const int idx = 2 * i + e;
            lv[idx] = l_;
            tt[idx] = tc;
            u[idx]  = l_ - 0.5f * (z1 * z1 + z2 * z2) - LOG_2PI_F;
        }
    }

    float mu_ = u[0], ml_ = lv[0];
    #pragma unroll
    for (int c = 1; c < 10; ++c) { mu_ = fmaxf(mu_, u[c]); ml_ = fmaxf(ml_, lv[c]); }
    mu_ = fmaxf(mu_, __shfl_xor(mu_, 1, 64));
    ml_ = fmaxf(ml_, __shfl_xor(ml_, 1, 64));
    const float mhat = mu_ + TMAX_LOG_F;

    float s1 = 0.0f, s2 = 0.0f;
    #pragma unroll
    for (int c = 0; c < 10; ++c) {
        s1 += tt[c] * __expf(u[c] - mhat);
        s2 += __expf(lv[c] - ml_);
    }
    s1 += __shfl_xor(s1, 1, 64);
    s2 += __shfl_xor(s2, 1, 64);

    const float logp = (mhat + __logf(s1)) - (ml_ + __logf(s2));

    // ---- pen loss (direct global, tiny) ----
    const float* pr = pen + (size_t)r * 3;
    const float q0 = pr[0], q1 = pr[1], q2 = pr[2];
    const float mq = fmaxf(fmaxf(q0, q1), q2);
    const float lseq = mq + __logf(__expf(q0 - mq) + __expf(q1 - mq) + __expf(q2 - mq));
    const float penv = pt0 * (q0 - lseq) + pt1 * (q1 - lseq) + pt2 * (q2 - lseq);

    float accp = logp * 0.5f;
    float acce = penv * 0.5f;

    // ---- block reduction ----
    const int lane = t & 63;
    const int wid  = t >> 6;
    #pragma unroll
    for (int off = 32; off > 0; off >>= 1) {
        accp += __shfl_down(accp, off, 64);
        acce += __shfl_down(acce, off, 64);
    }
    if (lane == 0) { s_pos[wid] = accp; s_pen[wid] = acce; }
    __syncthreads();
    if (t == 0) {
        partials[blockIdx.x * 2 + 0] = s_pos[0] + s_pos[1] + s_pos[2] + s_pos[3];
        partials[blockIdx.x * 2 + 1] = s_pen[0] + s_pen[1] + s_pen[2] + s_pen[3];
    }
}

__global__ __launch_bounds__(256) void sketch_reduce_kernel(
    const float* __restrict__ partials, float* __restrict__ out)
{
    float tp = 0.0f, te = 0.0f;
    for (int i = threadIdx.x; i < NBLK; i += 256) {
        tp += partials[2 * i + 0];
        te += partials[2 * i + 1];
    }
    #pragma unroll
    for (int off = 32; off > 0; off >>= 1) {
        tp += __shfl_down(tp, off, 64);
        te += __shfl_down(te, off, 64);
    }
    __shared__ float sp[4], se[4];
    const int lane = threadIdx.x & 63;
    const int wid  = threadIdx.x >> 6;
    if (lane == 0) { sp[wid] = tp; se[wid] = te; }
    __syncthreads();
    if (threadIdx.x == 0) {
        const float P = sp[0] + sp[1] + sp[2] + sp[3];
        const float E = se[0] + se[1] + se[2] + se[3];
        out[0] = -P / (float)NROWS;
        out[1] = -E / (float)NROWS;
    }
}

extern "C" void kernel_launch(void* const* d_in, const int* in_sizes, int n_in,
                              void* d_out, int out_size, void* d_ws, size_t ws_size,
                              hipStream_t stream) {
    const float* xs     = (const float*)d_in[0];
    const float* logits = (const float*)d_in[1];
    const float* mus    = (const float*)d_in[2];
    const float* sx     = (const float*)d_in[3];
    const float* sy     = (const float*)d_in[4];
    const float* sxy    = (const float*)d_in[5];
    const float* pen    = (const float*)d_in[6];
    float* out = (float*)d_out;
    float* partials = (float*)d_ws;          // NBLK * 2 floats = 32 KiB

    sketch_loss_kernel<<<NBLK, BLOCK, 0, stream>>>(xs, logits, mus, sx, sy, sxy, pen, partials);
    sketch_reduce_kernel<<<1, 256, 0, stream>>>(partials, out);
}

// Round 6
// 47.954 us; speedup vs baseline: 1.0855x; 1.0855x over previous
//
#include <hip/hip_runtime.h>
#include <math.h>

static constexpr int S_LEN = 2048;
static constexpr int NROWS = 256 * 2048;           // B*S
static constexpr int TILE  = 64;                   // rows per tile
static constexpr int BLOCK = 256;                  // 4 lanes per row
static constexpr int NBLOCKS = 512;                // exactly 2 per CU (persistent)
static constexpr int TPB   = NROWS / TILE / NBLOCKS;  // 16 tiles per block
static constexpr int BUF_FLOATS = 8192;            // 32 KB per buffer

// per-buffer float offsets (concatenated regions, 64-row tile)
static constexpr int OLG  = 0;      // 64*20 = 1280
static constexpr int OSX  = 1280;
static constexpr int OSY  = 2560;
static constexpr int OSW  = 3840;
static constexpr int OMU  = 5120;   // 64*40 = 2560
static constexpr int OXS  = 7680;   // 64*5  = 320
static constexpr int OPEN = 8000;   // 64*3  = 192 -> ends at 8192 exactly

static constexpr float SIGMA_MIN_F = 0.01f;
static constexpr float LOG_2PI_F   = 1.8378770664093453f;
static constexpr float TMAX_LOG_F  = 9.2103403719761836f;   // log(1e4) >= log(1/(sx*sy))

#define AS1 __attribute__((address_space(1)))
#define AS3 __attribute__((address_space(3)))
__device__ __forceinline__ void gl_lds16(const float* g, float* l) {
    __builtin_amdgcn_global_load_lds((const AS1 void*)g, (AS3 void*)l, 16, 0, 0);
}

// 8 uniform 16B slots per thread: slot = s*256 + t, float off f = slot*4
__device__ __forceinline__ void stage_tile(float* buf, int t, long r0,
    const float* xs, const float* lg, const float* sx, const float* sy,
    const float* sw, const float* mu, const float* pen)
{
    const float* plg = lg  + r0 * 20;
    const float* psx = sx  + r0 * 20;
    const float* psy = sy  + r0 * 20;
    const float* psw = sw  + r0 * 20;
    const float* pmu = mu  + r0 * 40;
    const float* pxs = xs  + r0 * 5;
    const float* ppn = pen + r0 * 3;
    #pragma unroll
    for (int s = 0; s < 8; ++s) {
        const int f = s * 1024 + t * 4;
        const float* src =
            (f < OSX)  ? plg + f :
            (f < OSY)  ? psx + (f - OSX) :
            (f < OSW)  ? psy + (f - OSY) :
            (f < OMU)  ? psw + (f - OSW) :
            (f < OXS)  ? pmu + (f - OMU) :
            (f < OPEN) ? pxs + (f - OXS) :
                         ppn + (f - OPEN);
        gl_lds16(src, buf + f);   // HW: firstlane base + lane*16 == buf + f (consecutive)
    }
}

__global__ __launch_bounds__(BLOCK) void sketch_loss_kernel(
    const float* __restrict__ xs,
    const float* __restrict__ logits,
    const float* __restrict__ mus,
    const float* __restrict__ sxp,
    const float* __restrict__ syp,
    const float* __restrict__ sxyp,
    const float* __restrict__ pen,
    float* __restrict__ partials)
{
    __shared__ float lds[2 * BUF_FLOATS];
    __shared__ float s_pos[4], s_pen[4];

    const int t = threadIdx.x;
    const int k = t >> 2;            // row within tile (0..63)
    const int h = t & 3;             // quarter: components h, h+4, h+8, h+12, h+16
    const long tile0 = (long)blockIdx.x * TPB;

    float accp = 0.0f, acce = 0.0f;

    // -------- prologue: stage tile 0 and its xn --------
    {
        const long r0 = tile0 * TILE;
        stage_tile(lds, t, r0, xs, logits, sxp, syp, sxyp, mus, pen);
    }
    float xn0, xn1;
    {
        const int r  = (int)(tile0 * TILE) + k;
        const int rn = ((r & (S_LEN - 1)) == S_LEN - 1) ? r - (S_LEN - 1) : r + 1;
        xn0 = xs[rn * 5 + 0];
        xn1 = xs[rn * 5 + 1];
    }

    for (int i = 0; i < TPB; ++i) {
        const float* buf = lds + (i & 1) * BUF_FLOATS;
        float nxn0 = 0.0f, nxn1 = 0.0f;

        __builtin_amdgcn_sched_barrier(0);
        __builtin_amdgcn_s_barrier();            // A: all waves done computing tile i-1
        __builtin_amdgcn_sched_barrier(0);

        if (i + 1 < TPB) {
            const long nr0 = (tile0 + i + 1) * TILE;
            stage_tile(lds + ((i + 1) & 1) * BUF_FLOATS, t, nr0,
                       xs, logits, sxp, syp, sxyp, mus, pen);
            const int nr  = (int)nr0 + k;
            const int nrn = ((nr & (S_LEN - 1)) == S_LEN - 1) ? nr - (S_LEN - 1) : nr + 1;
            nxn0 = xs[nrn * 5 + 0];              // 2 scalar VMEM (20B stride, 8B-align unsafe)
            nxn1 = xs[nrn * 5 + 1];
            __builtin_amdgcn_sched_barrier(0);   // pin: exactly 10 VMEM issued above
            asm volatile("s_waitcnt vmcnt(10)" ::: "memory");  // stage(i)+xn(i) complete
        } else {
            __builtin_amdgcn_sched_barrier(0);
            asm volatile("s_waitcnt vmcnt(0)" ::: "memory");
        }
        __builtin_amdgcn_sched_barrier(0);
        __builtin_amdgcn_s_barrier();            // B: buf(cur) fully staged by all waves
        __builtin_amdgcn_sched_barrier(0);

        // -------- compute tile i --------
        const float x0  = buf[OXS + k * 5 + 0];
        const float x1  = buf[OXS + k * 5 + 1];
        const float pt0 = buf[OXS + k * 5 + 2];
        const float pt1 = buf[OXS + k * 5 + 3];
        const float pt2 = buf[OXS + k * 5 + 4];
        const float rel0 = xn0 - x0;
        const float rel1 = xn1 - x1;

        float u[5], tc[5], lvv[5];
        #pragma unroll
        for (int c = 0; c < 5; ++c) {
            const int j = h + 4 * c;             // stride-4 interleave -> 2-way banks (free)
            const float l_  = buf[OLG + k * 20 + j];
            const float sxv = buf[OSX + k * 20 + j];
            const float syv = buf[OSY + k * 20 + j];
            const float swv = buf[OSW + k * 20 + j];
            const float2 m2 = *(const float2*)&buf[OMU + k * 40 + 2 * j];

            const float sx = fmaxf(sxv, SIGMA_MIN_F);
            const float sy = fmaxf(syv, SIGMA_MIN_F);
            const float sw = fminf(fmaxf(swv, -SIGMA_MIN_F), SIGMA_MIN_F);
            const float tt = __builtin_amdgcn_rcpf(sx * sy);
            const float d1 = rel0 - m2.x;
            const float d2 = rel1 - m2.y;
            const float z1 = d1 * sy * tt;
            const float z2 = (d2 - sw * z1) * sx * tt;
            lvv[c] = l_;
            tc[c]  = tt;
            u[c]   = l_ - 0.5f * (z1 * z1 + z2 * z2) - LOG_2PI_F;
        }

        float mu_ = u[0], ml_ = lvv[0];
        #pragma unroll
        for (int c = 1; c < 5; ++c) { mu_ = fmaxf(mu_, u[c]); ml_ = fmaxf(ml_, lvv[c]); }
        mu_ = fmaxf(mu_, __shfl_xor(mu_, 1, 64));
        mu_ = fmaxf(mu_, __shfl_xor(mu_, 2, 64));
        ml_ = fmaxf(ml_, __shfl_xor(ml_, 1, 64));
        ml_ = fmaxf(ml_, __shfl_xor(ml_, 2, 64));
        const float mhat = mu_ + TMAX_LOG_F;

        float s1 = 0.0f, s2 = 0.0f;
        #pragma unroll
        for (int c = 0; c < 5; ++c) {
            s1 += tc[c] * __expf(u[c] - mhat);
            s2 += __expf(lvv[c] - ml_);
        }
        s1 += __shfl_xor(s1, 1, 64);
        s1 += __shfl_xor(s1, 2, 64);
        s2 += __shfl_xor(s2, 1, 64);
        s2 += __shfl_xor(s2, 2, 64);

        const float logp = (mhat + __logf(s1)) - (ml_ + __logf(s2));

        const float q0 = buf[OPEN + k * 3 + 0];
        const float q1 = buf[OPEN + k * 3 + 1];
        const float q2 = buf[OPEN + k * 3 + 2];
        const float mq = fmaxf(fmaxf(q0, q1), q2);
        const float lseq = mq + __logf(__expf(q0 - mq) + __expf(q1 - mq) + __expf(q2 - mq));
        const float penv = pt0 * (q0 - lseq) + pt1 * (q1 - lseq) + pt2 * (q2 - lseq);

        accp += logp * 0.25f;
        acce += penv * 0.25f;
        xn0 = nxn0;
        xn1 = nxn1;
    }

    // -------- block reduction --------
    const int lane = t & 63;
    const int wid  = t >> 6;
    #pragma unroll
    for (int off = 32; off > 0; off >>= 1) {
        accp += __shfl_down(accp, off, 64);
        acce += __shfl_down(acce, off, 64);
    }
    if (lane == 0) { s_pos[wid] = accp; s_pen[wid] = acce; }
    __syncthreads();
    if (t == 0) {
        partials[blockIdx.x * 2 + 0] = s_pos[0] + s_pos[1] + s_pos[2] + s_pos[3];
        partials[blockIdx.x * 2 + 1] = s_pen[0] + s_pen[1] + s_pen[2] + s_pen[3];
    }
}

__global__ __launch_bounds__(256) void sketch_reduce_kernel(
    const float* __restrict__ partials, float* __restrict__ out)
{
    float tp = 0.0f, te = 0.0f;
    for (int i = threadIdx.x; i < NBLOCKS; i += 256) {
        tp += partials[2 * i + 0];
        te += partials[2 * i + 1];
    }
    #pragma unroll
    for (int off = 32; off > 0; off >>= 1) {
        tp += __shfl_down(tp, off, 64);
        te += __shfl_down(te, off, 64);
    }
    __shared__ float sp[4], se[4];
    const int lane = threadIdx.x & 63;
    const int wid  = threadIdx.x >> 6;
    if (lane == 0) { sp[wid] = tp; se[wid] = te; }
    __syncthreads();
    if (threadIdx.x == 0) {
        const float P = sp[0] + sp[1] + sp[2] + sp[3];
        const float E = se[0] + se[1] + se[2] + se[3];
        out[0] = -P / (float)NROWS;
        out[1] = -E / (float)NROWS;
    }
}

extern "C" void kernel_launch(void* const* d_in, const int* in_sizes, int n_in,
                              void* d_out, int out_size, void* d_ws, size_t ws_size,
                              hipStream_t stream) {
    const float* xs     = (const float*)d_in[0];
    const float* logits = (const float*)d_in[1];
    const float* mus    = (const float*)d_in[2];
    const float* sx     = (const float*)d_in[3];
    const float* sy     = (const float*)d_in[4];
    const float* sxy    = (const float*)d_in[5];
    const float* pen    = (const float*)d_in[6];
    float* out = (float*)d_out;
    float* partials = (float*)d_ws;              // NBLOCKS*2 floats = 4 KiB

    sketch_loss_kernel<<<NBLOCKS, BLOCK, 0, stream>>>(xs, logits, mus, sx, sy, sxy, pen, partials);
    sketch_reduce_kernel<<<1, 256, 0, stream>>>(partials, out);
}